// Round 1
// baseline (310.501 us; speedup 1.0000x reference)
//
#include <hip/hip_runtime.h>
#include <hip/hip_bf16.h>

typedef __hip_bfloat16 bf16;
typedef __attribute__((ext_vector_type(8))) short bf16x8;
typedef __attribute__((ext_vector_type(4))) float floatx4;

#define ROWS 32768   // BATCH*N_MOL
#define KPAD 128     // padded d_ext (70 -> 128)

__device__ __forceinline__ float b2f(unsigned int u) {
  union { unsigned int i; float f; } x;
  x.i = u << 16;
  return x.f;
}

// ---------------- prep kernels ----------------
__global__ void prep_xe(const float* __restrict__ x, const float* __restrict__ pos,
                        bf16* __restrict__ xe) {
  int idx = blockIdx.x * blockDim.x + threadIdx.x;   // ROWS*KPAD threads
  int r = idx >> 7, col = idx & 127;
  float v;
  if (col < 64)       v = x[r * 64 + col];
  else if (col < 70)  v = pos[(r & 15) * 6 + (col - 64)];
  else                v = 0.f;
  xe[idx] = __float2bfloat16(v);
}

__global__ void prep_w1(const float* __restrict__ wk, const float* __restrict__ wq,
                        const float* __restrict__ wv, bf16* __restrict__ w1t) {
  int idx = blockIdx.x * blockDim.x + threadIdx.x;   // 1536*128 threads
  int n = idx >> 7, k = idx & 127;
  int z = n >> 9, nl = n & 511;
  const float* src = (z == 0) ? wk : (z == 1) ? wq : wv;
  float v = (k < 70) ? src[k * 512 + nl] : 0.f;
  w1t[idx] = __float2bfloat16(v);
}

__global__ void prep_w2(const float* __restrict__ wk, const float* __restrict__ wq,
                        const float* __restrict__ wv, bf16* __restrict__ w2t) {
  int idx = blockIdx.x * blockDim.x + threadIdx.x;   // 3*512*512 threads
  int z = idx >> 18, r2 = idx & 262143;
  int n = r2 >> 9, k = r2 & 511;
  const float* src = (z == 0) ? wk : (z == 1) ? wq : wv;
  w2t[idx] = __float2bfloat16(src[k * 512 + n]);
}

__global__ void prep_b(const float* bk1, const float* bq1, const float* bv1,
                       const float* bk2, const float* bq2, const float* bv2,
                       float* __restrict__ b1, float* __restrict__ b2) {
  int idx = blockIdx.x * blockDim.x + threadIdx.x;   // 3072 threads
  if (idx < 1536) {
    int z = idx >> 9, nl = idx & 511;
    const float* s = (z == 0) ? bk1 : (z == 1) ? bq1 : bv1;
    b1[idx] = s[nl];
  } else {
    int j = idx - 1536;
    int z = j >> 9, nl = j & 511;
    const float* s = (z == 0) ? bk2 : (z == 1) ? bq2 : bv2;
    b2[j] = s[nl];
  }
}

// ---------------- GEMM: C(MxN) = act(A(MxK) * Bt(NxK)^T + bias) ----------------
// 128x128 tile, 4 waves (each 64x64), mfma_f32_16x16x32_bf16, global_load_lds w16.
template<int SILU>
__global__ __launch_bounds__(256) void mlp_gemm(
    const bf16* __restrict__ A, int lda,
    const bf16* __restrict__ Bt,          // N x K row-major (ldb = K)
    const float* __restrict__ bias,       // length N
    bf16* __restrict__ C, int ldc, int K)
{
  __shared__ __align__(16) bf16 As[128 * 32];
  __shared__ __align__(16) bf16 Bs[128 * 32];
  const int tid  = threadIdx.x;
  const int wave = tid >> 6, lane = tid & 63;
  const int bm = blockIdx.x * 128;
  const int bn = blockIdx.y * 128;
  const int wm = (wave >> 1) * 64;
  const int wn = (wave & 1) * 64;

  floatx4 acc[4][4] = {};

  const int arow = lane >> 2;          // 0..15 row within 16-row chunk
  const int acol = (lane & 3) * 8;     // k-element offset (16B granules)

  for (int k0 = 0; k0 < K; k0 += 32) {
    __syncthreads();   // protect LDS from previous iteration's readers
    #pragma unroll
    for (int ch = 0; ch < 2; ++ch) {
      const int rb = wave * 32 + ch * 16;   // 16 rows per wave-call
      const bf16* ga = A  + (long)(bm + rb + arow) * lda + k0 + acol;
      const bf16* gb = Bt + (long)(bn + rb + arow) * K   + k0 + acol;
      __builtin_amdgcn_global_load_lds(
          (const __attribute__((address_space(1))) unsigned int*)ga,
          (__attribute__((address_space(3))) unsigned int*)(As + rb * 32), 16, 0, 0);
      __builtin_amdgcn_global_load_lds(
          (const __attribute__((address_space(1))) unsigned int*)gb,
          (__attribute__((address_space(3))) unsigned int*)(Bs + rb * 32), 16, 0, 0);
    }
    asm volatile("s_waitcnt vmcnt(0)" ::: "memory");
    __syncthreads();

    bf16x8 af[4], bfr[4];
    #pragma unroll
    for (int mi = 0; mi < 4; ++mi)
      af[mi] = *(const bf16x8*)(As + (wm + mi * 16 + (lane & 15)) * 32 + (lane >> 4) * 8);
    #pragma unroll
    for (int ni = 0; ni < 4; ++ni)
      bfr[ni] = *(const bf16x8*)(Bs + (wn + ni * 16 + (lane & 15)) * 32 + (lane >> 4) * 8);
    #pragma unroll
    for (int mi = 0; mi < 4; ++mi)
      #pragma unroll
      for (int ni = 0; ni < 4; ++ni)
        acc[mi][ni] = __builtin_amdgcn_mfma_f32_16x16x32_bf16(af[mi], bfr[ni], acc[mi][ni], 0, 0, 0);
  }

  // epilogue: C/D layout col = lane&15, row = (lane>>4)*4 + r  [verified m89/m91]
  #pragma unroll
  for (int mi = 0; mi < 4; ++mi) {
    #pragma unroll
    for (int ni = 0; ni < 4; ++ni) {
      const int nc = bn + wn + ni * 16 + (lane & 15);
      const float bv = bias[nc];
      #pragma unroll
      for (int r = 0; r < 4; ++r) {
        const long m = bm + wm + mi * 16 + (lane >> 4) * 4 + r;
        float v = acc[mi][ni][r] + bv;
        if (SILU) v = v / (1.f + __expf(-v));   // x*sigmoid(x)
        C[m * (long)ldc + nc] = __float2bfloat16(v);
      }
    }
  }
}

// ---------------- attention: one block per batch item ----------------
// kqv: (3, 32768, 512) bf16.  out: (2048, 16, 64) f32.
#define S2W 257   // LDS row stride in 32-bit words (2 bf16/word); 257 % 32 == 1 -> conflict-free

__global__ __launch_bounds__(512) void attn_kernel(
    const bf16* __restrict__ kqv,
    const float* __restrict__ flow_mask,
    float* __restrict__ out)
{
  __shared__ unsigned int kw_s[16 * S2W];
  __shared__ unsigned int qw_s[16 * S2W];
  __shared__ unsigned int vw_s[16 * S2W];
  __shared__ float ww[16 * 16 * 8];   // [i][j][c]
  __shared__ float fm[16];

  const int tid = threadIdx.x;
  const int b   = blockIdx.x;

  // ---- stage k,q,v (each 16x512 bf16 = 16KB) into LDS as packed words ----
  {
    const int row = tid >> 5;            // 0..15
    const int cw  = (tid & 31) * 8;      // word offset within row (256 words/row)
    const unsigned int* g = (const unsigned int*)kqv;
    const long wb = (long)b * 4096 + row * 256 + cw;
    const uint4* gk = (const uint4*)(g + wb);
    const uint4* gq = (const uint4*)(g + 8388608  + wb);
    const uint4* gv = (const uint4*)(g + 16777216 + wb);
    uint4 k0 = gk[0], k1 = gk[1];
    uint4 q0 = gq[0], q1 = gq[1];
    uint4 v0 = gv[0], v1 = gv[1];
    unsigned int* dk = kw_s + row * S2W + cw;
    unsigned int* dq = qw_s + row * S2W + cw;
    unsigned int* dv = vw_s + row * S2W + cw;
    dk[0]=k0.x; dk[1]=k0.y; dk[2]=k0.z; dk[3]=k0.w; dk[4]=k1.x; dk[5]=k1.y; dk[6]=k1.z; dk[7]=k1.w;
    dq[0]=q0.x; dq[1]=q0.y; dq[2]=q0.z; dq[3]=q0.w; dq[4]=q1.x; dq[5]=q1.y; dq[6]=q1.z; dq[7]=q1.w;
    dv[0]=v0.x; dv[1]=v0.y; dv[2]=v0.z; dv[3]=v0.w; dv[4]=v1.x; dv[5]=v1.y; dv[6]=v1.z; dv[7]=v1.w;
  }
  if (tid < 16) fm[tid] = flow_mask[tid];
  __syncthreads();

  // ---- scores: arg[i,j,c] = fm[i]*fm[j]*dot(k[i,c,:],q[j,c,:])/8; w = softplus+1e-5, diag=0 ----
  {
    const int i  = tid >> 5;
    const int j  = (tid >> 1) & 15;
    const int chh = tid & 1;
    const float mm = fm[i] * fm[j] * 0.125f;
    const unsigned int* kp = kw_s + i * S2W;
    const unsigned int* qp = qw_s + j * S2W;
    #pragma unroll
    for (int cc = 0; cc < 4; ++cc) {
      const int c = chh * 4 + cc;
      float s = 0.f;
      #pragma unroll 8
      for (int a2 = 0; a2 < 32; ++a2) {
        const unsigned int kk = kp[c * 32 + a2];
        const unsigned int qq = qp[c * 32 + a2];
        s += b2f(kk & 0xffffu) * b2f(qq & 0xffffu);
        s += b2f(kk >> 16)     * b2f(qq >> 16);
      }
      const float arg = s * mm;
      float w = fmaxf(arg, 0.f) + log1pf(__expf(-fabsf(arg))) + 1e-5f;  // stable softplus
      if (i == j) w = 0.f;
      ww[(i * 16 + j) * 8 + c] = w;
    }
  }
  __syncthreads();

  // ---- normalize over j per (i,c); fold fm[j] for the PV step ----
  if (tid < 128) {
    const int i = tid >> 3, c = tid & 7;
    float s = 0.f;
    #pragma unroll
    for (int j = 0; j < 16; ++j) s += ww[(i * 16 + j) * 8 + c];
    const float inv = 1.f / s;
    #pragma unroll
    for (int j = 0; j < 16; ++j) ww[(i * 16 + j) * 8 + c] *= inv * fm[j];
  }
  __syncthreads();

  // ---- PV: out[i,d] = sum_{j,c} w[i,j,c] * v[j,c,d]; 2 adjacent d per thread ----
  {
    const int i  = tid >> 5;
    const int dh = tid & 31;
    float a0 = 0.f, a1 = 0.f;
    for (int j = 0; j < 16; ++j) {
      const unsigned int* vp = vw_s + j * S2W;
      const float* wp = ww + (i * 16 + j) * 8;
      #pragma unroll
      for (int c = 0; c < 8; ++c) {
        const float w = wp[c];
        const unsigned int vv = vp[c * 32 + dh];
        a0 += w * b2f(vv & 0xffffu);
        a1 += w * b2f(vv >> 16);
      }
    }
    float2 r; r.x = a0; r.y = a1;
    *(float2*)(out + (long)b * 1024 + i * 64 + dh * 2) = r;
  }
}

// ---------------- launch ----------------
extern "C" void kernel_launch(void* const* d_in, const int* in_sizes, int n_in,
                              void* d_out, int out_size, void* d_ws, size_t ws_size,
                              hipStream_t stream) {
  const float* x    = (const float*)d_in[0];
  const float* fmk  = (const float*)d_in[1];
  const float* Wk_h = (const float*)d_in[2];
  const float* bk_h = (const float*)d_in[3];
  const float* Wk_o = (const float*)d_in[4];
  const float* bk_o = (const float*)d_in[5];
  const float* Wq_h = (const float*)d_in[6];
  const float* bq_h = (const float*)d_in[7];
  const float* Wq_o = (const float*)d_in[8];
  const float* bq_o = (const float*)d_in[9];
  const float* Wv_h = (const float*)d_in[10];
  const float* bv_h = (const float*)d_in[11];
  const float* Wv_o = (const float*)d_in[12];
  const float* bv_o = (const float*)d_in[13];
  const float* pos  = (const float*)d_in[14];
  float* out = (float*)d_out;

  // workspace layout (bytes)
  char* ws = (char*)d_ws;
  bf16*  xe  = (bf16*)(ws + 0);           //  8,388,608  (32768 x 128)
  bf16*  W1t = (bf16*)(ws + 8388608);     //    393,216  (1536 x 128)
  bf16*  W2t = (bf16*)(ws + 8781824);     //  1,572,864  (3 x 512 x 512)
  float* b1  = (float*)(ws + 10354688);   //      6,144
  float* b2  = (float*)(ws + 10360832);   //      6,144
  bf16*  hid = (bf16*)(ws + 10366976);    // 33,554,432  (32768 x 512, reused per branch)
  bf16*  kqv = (bf16*)(ws + 43921408);    // 100,663,296 (3 x 32768 x 512)
  if (ws_size < 144584704ULL) return;     // recognizable clean-fail: out stays zero

  prep_xe<<<ROWS * KPAD / 256, 256, 0, stream>>>(x, pos, xe);
  prep_w1<<<1536 * 128 / 256, 256, 0, stream>>>(Wk_h, Wq_h, Wv_h, W1t);
  prep_w2<<<3 * 512 * 512 / 256, 256, 0, stream>>>(Wk_o, Wq_o, Wv_o, W2t);
  prep_b<<<12, 256, 0, stream>>>(bk_h, bq_h, bv_h, bk_o, bq_o, bv_o, b1, b2);

  for (int z = 0; z < 3; ++z) {
    mlp_gemm<1><<<dim3(ROWS / 128, 4), 256, 0, stream>>>(
        xe, KPAD, W1t + (long)z * 512 * KPAD, b1 + z * 512, hid, 512, KPAD);
    mlp_gemm<0><<<dim3(ROWS / 128, 4), 256, 0, stream>>>(
        hid, 512, W2t + (long)z * 512 * 512, b2 + z * 512,
        kqv + (long)z * ROWS * 512, 512, 512);
  }

  attn_kernel<<<2048, 512, 0, stream>>>(kqv, fmk, out);
}

// Round 4
// 248.266 us; speedup vs baseline: 1.2507x; 1.2507x over previous
//
#include <hip/hip_runtime.h>
#include <hip/hip_bf16.h>

typedef __hip_bfloat16 bf16;
typedef __attribute__((ext_vector_type(8))) short bf16x8;
typedef __attribute__((ext_vector_type(4))) float floatx4;
typedef unsigned short ushort;

#define ROWS 32768   // BATCH*N_MOL
#define KPAD 128     // padded d_ext (70 -> 128)

// ---------------- single prep kernel ----------------
// ranges: [0,4194304) xe | [..,+786432) w2t | [..,+196608) w1t | [..,+3072) biases
__global__ void prep_all(
    const float* __restrict__ x, const float* __restrict__ pos,
    const float* __restrict__ Wk_h, const float* __restrict__ Wq_h, const float* __restrict__ Wv_h,
    const float* __restrict__ Wk_o, const float* __restrict__ Wq_o, const float* __restrict__ Wv_o,
    const float* __restrict__ bk1, const float* __restrict__ bq1, const float* __restrict__ bv1,
    const float* __restrict__ bk2, const float* __restrict__ bq2, const float* __restrict__ bv2,
    bf16* __restrict__ xe, bf16* __restrict__ w1t, bf16* __restrict__ w2t,
    float* __restrict__ b1, float* __restrict__ b2)
{
  int idx = blockIdx.x * 256 + threadIdx.x;
  if (idx < 4194304) {                      // xe: (32768 x 128)
    int r = idx >> 7, col = idx & 127;
    float v;
    if (col < 64)      v = x[r * 64 + col];
    else if (col < 70) v = pos[(r & 15) * 6 + (col - 64)];
    else               v = 0.f;
    xe[idx] = __float2bfloat16(v);
  } else if (idx < 4194304 + 786432) {      // w2t: (3 x 512 x 512) N-major
    int i = idx - 4194304;
    int z = i >> 18, r2 = i & 262143;
    int n = r2 >> 9, k = r2 & 511;
    const float* src = (z == 0) ? Wk_o : (z == 1) ? Wq_o : Wv_o;
    w2t[i] = __float2bfloat16(src[k * 512 + n]);
  } else if (idx < 4194304 + 786432 + 196608) {   // w1t: (1536 x 128)
    int i = idx - 4194304 - 786432;
    int n = i >> 7, k = i & 127;
    int z = n >> 9, nl = n & 511;
    const float* src = (z == 0) ? Wk_h : (z == 1) ? Wq_h : Wv_h;
    float v = (k < 70) ? src[k * 512 + nl] : 0.f;
    w1t[i] = __float2bfloat16(v);
  } else if (idx < 4194304 + 786432 + 196608 + 3072) {
    int i = idx - 4194304 - 786432 - 196608;
    if (i < 1536) {
      int z = i >> 9, nl = i & 511;
      const float* s = (z == 0) ? bk1 : (z == 1) ? bq1 : bv1;
      b1[i] = s[nl];
    } else {
      int j = i - 1536;
      int z = j >> 9, nl = j & 511;
      const float* s = (z == 0) ? bk2 : (z == 1) ? bq2 : bv2;
      b2[j] = s[nl];
    }
  }
}

// ---------------- GEMM: C(MxN) = act(A(MxK) * Bt(NxK)^T + bias) ----------------
// 128x128 tile, 4 waves, mfma_f32_16x16x32_bf16, global_load_lds w16.
// SPLITZ: blockIdx.y = z*4 + nb; branch z offsets A columns (+z*512), Bt (+z*512*K),
// bias (+z*512), C (+z*ROWS*512).
template<int SILU, int SPLITZ>
__global__ __launch_bounds__(256) void mlp_gemm(
    const bf16* __restrict__ A, int lda,
    const bf16* __restrict__ Bt, const float* __restrict__ bias,
    bf16* __restrict__ C, int ldc, int K)
{
  __shared__ __align__(16) bf16 As[128 * 32];
  __shared__ __align__(16) bf16 Bs[128 * 32];
  const int tid  = threadIdx.x;
  const int wave = tid >> 6, lane = tid & 63;

  int bnb = blockIdx.y;
  const bf16* Ap = A; const bf16* Btp = Bt; const float* biasp = bias; bf16* Cp = C;
  if (SPLITZ) {
    const int z = blockIdx.y >> 2;
    bnb = blockIdx.y & 3;
    Ap    += z * 512;                 // column offset into A (lda spans all branches)
    Btp   += (long)z * 512 * K;
    biasp += z * 512;
    Cp    += (long)z * ROWS * 512;
  }
  const int bm = blockIdx.x * 128;
  const int bn = bnb * 128;
  const int wm = (wave >> 1) * 64;
  const int wn = (wave & 1) * 64;

  floatx4 acc[4][4] = {};

  const int arow = lane >> 2;          // 0..15 row within 16-row chunk
  const int acol = (lane & 3) * 8;     // k-element offset (16B granules)

  for (int k0 = 0; k0 < K; k0 += 32) {
    __syncthreads();
    #pragma unroll
    for (int ch = 0; ch < 2; ++ch) {
      const int rb = wave * 32 + ch * 16;
      const bf16* ga = Ap  + (long)(bm + rb + arow) * lda + k0 + acol;
      const bf16* gb = Btp + (long)(bn + rb + arow) * K   + k0 + acol;
      __builtin_amdgcn_global_load_lds(
          (const __attribute__((address_space(1))) unsigned int*)ga,
          (__attribute__((address_space(3))) unsigned int*)(As + rb * 32), 16, 0, 0);
      __builtin_amdgcn_global_load_lds(
          (const __attribute__((address_space(1))) unsigned int*)gb,
          (__attribute__((address_space(3))) unsigned int*)(Bs + rb * 32), 16, 0, 0);
    }
    asm volatile("s_waitcnt vmcnt(0)" ::: "memory");
    __syncthreads();

    bf16x8 af[4], bfr[4];
    #pragma unroll
    for (int mi = 0; mi < 4; ++mi)
      af[mi] = *(const bf16x8*)(As + (wm + mi * 16 + (lane & 15)) * 32 + (lane >> 4) * 8);
    #pragma unroll
    for (int ni = 0; ni < 4; ++ni)
      bfr[ni] = *(const bf16x8*)(Bs + (wn + ni * 16 + (lane & 15)) * 32 + (lane >> 4) * 8);
    #pragma unroll
    for (int mi = 0; mi < 4; ++mi)
      #pragma unroll
      for (int ni = 0; ni < 4; ++ni)
        acc[mi][ni] = __builtin_amdgcn_mfma_f32_16x16x32_bf16(af[mi], bfr[ni], acc[mi][ni], 0, 0, 0);
  }

  #pragma unroll
  for (int mi = 0; mi < 4; ++mi) {
    #pragma unroll
    for (int ni = 0; ni < 4; ++ni) {
      const int nc = bn + wn + ni * 16 + (lane & 15);
      const float bv = biasp[nc];
      #pragma unroll
      for (int r = 0; r < 4; ++r) {
        const long m = bm + wm + mi * 16 + (lane >> 4) * 4 + r;
        float v = acc[mi][ni][r] + bv;
        if (SILU) v = v / (1.f + __expf(-v));
        Cp[m * (long)ldc + nc] = __float2bfloat16(v);
      }
    }
  }
}

// ---------------- MFMA attention: one 256-thread block per batch ----------------
// kqv: (3, 32768, 512) bf16.  out: (2048, 16, 64) f32.
#define ATS 520   // k/q/v LDS row stride in bf16 (260 words == 4 mod 32 -> 2-way max)

__global__ __launch_bounds__(256) void attn_mfma(
    const bf16* __restrict__ kqv,
    const float* __restrict__ flow_mask,
    float* __restrict__ out)
{
  __shared__ ushort ks[16 * ATS];
  __shared__ ushort qs[16 * ATS];
  __shared__ ushort vs[16 * ATS];
  __shared__ ushort wn_s[4 * 16 * 40];   // [hp][i][kk], stride 40 (20 words == 2-way)
  __shared__ float  fm_s[16];

  const int tid  = threadIdx.x;
  const int lane = tid & 63;
  const int wave = tid >> 6;          // 0..3
  const int b    = blockIdx.x;
  const long rowbase = (long)b * 16 * 512;

  // ---- stage k,q,v: contiguous granule loads, contiguous LDS writes ----
  {
    const uint4* gk = (const uint4*)(kqv + rowbase);
    const uint4* gq = (const uint4*)(kqv + 16777216 + rowbase);
    const uint4* gv = (const uint4*)(kqv + 33554432 + rowbase);
    #pragma unroll
    for (int g = 0; g < 4; ++g) {
      const int gid = tid + g * 256;          // 0..1023
      const int row = gid >> 6, colg = gid & 63;
      uint4 kv = gk[row * 64 + colg];
      uint4 qv = gq[row * 64 + colg];
      uint4 vv = gv[row * 64 + colg];
      *(uint4*)&ks[row * ATS + colg * 8] = kv;
      *(uint4*)&qs[row * ATS + colg * 8] = qv;
      *(uint4*)&vs[row * ATS + colg * 8] = vv;
    }
  }
  if (tid < 16) fm_s[tid] = flow_mask[tid];
  __syncthreads();

  const int jcol = lane & 15;         // N index (j for QK, d-offset for PV)
  const int rgrp = lane >> 4;         // 0..3
  const int ko   = rgrp * 8;          // K fragment offset

  // ---- QK^T + softplus + mask + j-normalize; store wn as bf16 A-fragments ----
  {
    const float fmj = fm_s[jcol];
    #pragma unroll
    for (int h = 0; h < 2; ++h) {
      const int c = wave + h * 4;     // head
      floatx4 acc = {};
      const ushort* kr = ks + jcol * ATS + c * 64 + ko;   // A: K-matrix rows (i = lane&15)
      const ushort* qr = qs + jcol * ATS + c * 64 + ko;   // B: Q-matrix cols (j = lane&15)
      bf16x8 a0 = *(const bf16x8*)(kr);
      bf16x8 a1 = *(const bf16x8*)(kr + 32);
      bf16x8 b0 = *(const bf16x8*)(qr);
      bf16x8 b1 = *(const bf16x8*)(qr + 32);
      acc = __builtin_amdgcn_mfma_f32_16x16x32_bf16(a0, b0, acc, 0, 0, 0);
      acc = __builtin_amdgcn_mfma_f32_16x16x32_bf16(a1, b1, acc, 0, 0, 0);

      // lane holds col j=jcol, rows i = rgrp*4 + r
      float w[4], s[4];
      #pragma unroll
      for (int r = 0; r < 4; ++r) {
        const int i = rgrp * 4 + r;
        float arg = acc[r] * (fm_s[i] * fmj * 0.125f);
        float sp  = fmaxf(arg, 0.f) + log1pf(__expf(-fabsf(arg)));
        float wv  = sp + 1e-5f;
        if (i == jcol) wv = 0.f;      // mask_self
        w[r] = wv; s[r] = wv;
      }
      #pragma unroll
      for (int m = 1; m < 16; m <<= 1) {
        #pragma unroll
        for (int r = 0; r < 4; ++r) s[r] += __shfl_xor(s[r], m);
      }
      const int hp = c >> 1, chl = c & 1;
      #pragma unroll
      for (int r = 0; r < 4; ++r) {
        const int i = rgrp * 4 + r;
        float wnv = w[r] / s[r] * fmj;       // fold fm[j] for PV
        unsigned int bi = __builtin_bit_cast(unsigned int, wnv);
        ushort bv = (ushort)((bi + 0x7fffu + ((bi >> 16) & 1u)) >> 16);  // RNE bf16
        wn_s[hp * 640 + i * 40 + chl * 16 + jcol] = bv;
      }
    }
  }
  __syncthreads();

  // ---- PV: O[i, dbase+jcol] = sum_hp  Wn_hp(16x32) x Vpair(32x16) ----
  {
    const int dbase = wave * 16;
    const int dcol  = dbase + jcol;
    floatx4 o = {};
    #pragma unroll
    for (int hp = 0; hp < 4; ++hp) {
      bf16x8 af = *(const bf16x8*)(wn_s + hp * 640 + jcol * 40 + ko);
      const int c  = 2 * hp + (ko >> 4);
      const int jb = ko & 15;
      bf16x8 bf;
      #pragma unroll
      for (int e = 0; e < 8; ++e)
        bf[e] = (short)vs[(jb + e) * ATS + c * 64 + dcol];
      o = __builtin_amdgcn_mfma_f32_16x16x32_bf16(af, bf, o, 0, 0, 0);
    }
    float* ob = out + (long)b * 1024 + dcol;
    #pragma unroll
    for (int r = 0; r < 4; ++r) ob[(rgrp * 4 + r) * 64] = o[r];
  }
}

// ---------------- launch ----------------
extern "C" void kernel_launch(void* const* d_in, const int* in_sizes, int n_in,
                              void* d_out, int out_size, void* d_ws, size_t ws_size,
                              hipStream_t stream) {
  const float* x    = (const float*)d_in[0];
  const float* fmk  = (const float*)d_in[1];
  const float* Wk_h = (const float*)d_in[2];
  const float* bk_h = (const float*)d_in[3];
  const float* Wk_o = (const float*)d_in[4];
  const float* bk_o = (const float*)d_in[5];
  const float* Wq_h = (const float*)d_in[6];
  const float* bq_h = (const float*)d_in[7];
  const float* Wq_o = (const float*)d_in[8];
  const float* bq_o = (const float*)d_in[9];
  const float* Wv_h = (const float*)d_in[10];
  const float* bv_h = (const float*)d_in[11];
  const float* Wv_o = (const float*)d_in[12];
  const float* bv_o = (const float*)d_in[13];
  const float* pos  = (const float*)d_in[14];
  float* out = (float*)d_out;

  char* ws = (char*)d_ws;
  bf16*  xe  = (bf16*)(ws + 0);           //   8,388,608
  bf16*  W1t = (bf16*)(ws + 8388608);     //     393,216
  bf16*  W2t = (bf16*)(ws + 8781824);     //   1,572,864
  float* b1  = (float*)(ws + 10354688);   //       6,144
  float* b2  = (float*)(ws + 10360832);   //       6,144
  const bool big = (ws_size >= 211693568ULL);

  prep_all<<<20236, 256, 0, stream>>>(x, pos, Wk_h, Wq_h, Wv_h, Wk_o, Wq_o, Wv_o,
                                      bk_h, bq_h, bv_h, bk_o, bq_o, bv_o,
                                      xe, W1t, W2t, b1, b2);

  if (big) {
    bf16* hid = (bf16*)(ws + 10366976);     // 100,663,296 (32768 x 1536)
    bf16* kqv = (bf16*)(ws + 111030272);    // 100,663,296 (3 x 32768 x 512)
    // layer 1: all branches in one GEMM, N=1536
    mlp_gemm<1, 0><<<dim3(ROWS / 128, 12), 256, 0, stream>>>(
        xe, KPAD, W1t, b1, hid, 1536, KPAD);
    // layer 2: 3 branches via grid.y (z = y>>2)
    mlp_gemm<0, 1><<<dim3(ROWS / 128, 12), 256, 0, stream>>>(
        hid, 1536, W2t, b2, kqv, 512, 512);
    attn_mfma<<<2048, 256, 0, stream>>>(kqv, fmk, out);
  } else {
    if (ws_size < 144584704ULL) return;
    bf16* hid = (bf16*)(ws + 10366976);     //  33,554,432 (32768 x 512, reused)
    bf16* kqv = (bf16*)(ws + 43921408);     // 100,663,296
    for (int z = 0; z < 3; ++z) {
      mlp_gemm<1, 0><<<dim3(ROWS / 128, 4), 256, 0, stream>>>(
          xe, KPAD, W1t + (long)z * 512 * KPAD, b1 + z * 512, hid, 512, KPAD);
      mlp_gemm<0, 0><<<dim3(ROWS / 128, 4), 256, 0, stream>>>(
          hid, 512, W2t + (long)z * 512 * 512, b2 + z * 512,
          kqv + (long)z * ROWS * 512, 512, 512);
    }
    attn_mfma<<<2048, 256, 0, stream>>>(kqv, fmk, out);
  }
}